// Round 1
// baseline (27.629 us; speedup 1.0000x reference)
//
#include <hip/hip_runtime.h>
#include <hip/hip_bf16.h>

#define N_SEG 64
#define N_LMK 82
#define N_P   164      // 82 landmarks * 2 coords
#define N_CHUNK 16
#define ROW 1629       // 543 * 3 floats per frame

__device__ __constant__ int LIPS[40] = {
    61, 185, 40, 39, 37, 0, 267, 269, 270, 409, 291, 146, 91, 181, 84, 17,
    314, 405, 321, 375, 78, 191, 80, 81, 82, 13, 312, 311, 310, 415, 95, 88,
    178, 87, 14, 317, 402, 318, 324, 308};

// ws layout: [0, 64*164)      sum
//            [64*164, 2*..)   sumsq
//            [2*64*164, 3*..) cnt
__global__ __launch_bounds__(192) void accum_kernel(
    const float* __restrict__ frames, float* __restrict__ ws, int T) {
    const int s   = blockIdx.x;   // segment
    const int kc  = blockIdx.y;   // frame chunk within segment
    const int tid = threadIdx.x;
    if (tid >= N_P) return;

    const int l = tid >> 1;
    const int c = tid & 1;
    int lm;
    if (l < 21)      lm = 468 + l;           // left hand
    else if (l < 42) lm = 501 + l;           // right hand: 522 + (l-21)
    else             lm = LIPS[l - 42];      // lips
    const int off = lm * 3 + c;

    // boundaries: exact float32 replication of jnp.linspace(...).astype(int32)
    const float step = (float)(T - 1) / 64.0f;
    const int lo = (int)((float)s * step);
    const int hi = (int)((float)(s + 1) * step);

    float sum = 0.f, sq = 0.f, cnt = 0.f;
    for (int f = lo + kc; f < hi; f += N_CHUNK) {
        float v = frames[(size_t)f * ROW + off];
        if (v == v) {           // !isnan
            sum += v;
            sq  += v * v;
            cnt += 1.f;
        }
    }
    const int idx = s * N_P + tid;
    atomicAdd(&ws[idx],               sum);
    atomicAdd(&ws[N_SEG * N_P + idx], sq);
    atomicAdd(&ws[2 * N_SEG * N_P + idx], cnt);
}

__global__ __launch_bounds__(256) void finalize_kernel(
    const float* __restrict__ ws, float* __restrict__ out) {
    const int i = blockIdx.x * blockDim.x + threadIdx.x;
    if (i >= N_SEG * N_P) return;
    const int s = i / N_P;
    const int p = i % N_P;

    const float s1  = ws[i];
    const float s2  = ws[N_SEG * N_P + i];
    const float cnt = ws[2 * N_SEG * N_P + i];

    float mean = s1 / cnt;                         // cnt==0 -> nan
    float var  = fmaxf(s2 / cnt - mean * mean, 0.f);
    float sd   = sqrtf(var);
    if (!(mean == mean)) mean = 0.f;
    if (!(sd == sd))     sd   = 0.f;

    // stats layout: (64, 164, 2) -> (64, 328); first 82 l-slots mean, next 82 std
    out[s * 328 + p]       = mean;
    out[s * 328 + 164 + p] = sd;
}

extern "C" void kernel_launch(void* const* d_in, const int* in_sizes, int n_in,
                              void* d_out, int out_size, void* d_ws, size_t ws_size,
                              hipStream_t stream) {
    const float* frames = (const float*)d_in[0];
    float* out = (float*)d_out;
    float* ws  = (float*)d_ws;
    const int T = in_sizes[0] / ROW;   // 32768

    hipMemsetAsync(ws, 0, 3 * N_SEG * N_P * sizeof(float), stream);

    dim3 grid(N_SEG, N_CHUNK);
    accum_kernel<<<grid, 192, 0, stream>>>(frames, ws, T);

    finalize_kernel<<<(N_SEG * N_P + 255) / 256, 256, 0, stream>>>(ws, out);
}

// Round 2
// 25.050 us; speedup vs baseline: 1.1030x; 1.1030x over previous
//
#include <hip/hip_runtime.h>
#include <hip/hip_bf16.h>

#define N_SEG 64
#define N_P   164        // 82 landmarks * 2 coords
#define ROW   1629       // 543 * 3 floats per frame
#define N_CHUNK 32       // frame chunks per segment (partials path)
#define N_CHUNK_AT 16    // chunks for atomic fallback

__device__ __constant__ int LIPS[40] = {
    61, 185, 40, 39, 37, 0, 267, 269, 270, 409, 291, 146, 91, 181, 84, 17,
    314, 405, 321, 375, 78, 191, 80, 81, 82, 13, 312, 311, 310, 415, 95, 88,
    178, 87, 14, 317, 402, 318, 324, 308};

__device__ __forceinline__ int landmark_offset(int tid) {
    const int l = tid >> 1;
    const int c = tid & 1;
    int lm;
    if (l < 21)      lm = 468 + l;           // left hand
    else if (l < 42) lm = 501 + l;           // right hand: 522 + (l-21)
    else             lm = LIPS[l - 42];      // lips
    return lm * 3 + c;
}

__device__ __forceinline__ void seg_bounds(int s, int T, int* lo, int* hi) {
    const float step = (float)(T - 1) / 64.0f;   // exact linspace replication
    *lo = (int)((float)s * step);
    *hi = (int)((float)(s + 1) * step);
}

// ---------------- partials path (no memset, no atomics) ----------------
// ws layout: [(s*N_CHUNK + kc) * N_P + tid] * 3 + {sum, sumsq, cnt}
__global__ __launch_bounds__(192) void accum_part(
    const float* __restrict__ frames, float* __restrict__ ws, int T) {
    const int s   = blockIdx.x;
    const int kc  = blockIdx.y;
    const int tid = threadIdx.x;
    if (tid >= N_P) return;

    const int off = landmark_offset(tid);
    int lo, hi;
    seg_bounds(s, T, &lo, &hi);

    float sum = 0.f, sq = 0.f, cnt = 0.f;
    int f = lo + kc;
    // 4x unrolled: 4 independent loads in flight
    for (; f + 3 * N_CHUNK < hi; f += 4 * N_CHUNK) {
        float v0 = frames[(size_t)f * ROW + off];
        float v1 = frames[(size_t)(f + N_CHUNK) * ROW + off];
        float v2 = frames[(size_t)(f + 2 * N_CHUNK) * ROW + off];
        float v3 = frames[(size_t)(f + 3 * N_CHUNK) * ROW + off];
        if (v0 == v0) { sum += v0; sq = fmaf(v0, v0, sq); cnt += 1.f; }
        if (v1 == v1) { sum += v1; sq = fmaf(v1, v1, sq); cnt += 1.f; }
        if (v2 == v2) { sum += v2; sq = fmaf(v2, v2, sq); cnt += 1.f; }
        if (v3 == v3) { sum += v3; sq = fmaf(v3, v3, sq); cnt += 1.f; }
    }
    for (; f < hi; f += N_CHUNK) {
        float v = frames[(size_t)f * ROW + off];
        if (v == v) { sum += v; sq = fmaf(v, v, sq); cnt += 1.f; }
    }

    const size_t base = ((size_t)(s * N_CHUNK + kc) * N_P + tid) * 3;
    ws[base]     = sum;
    ws[base + 1] = sq;
    ws[base + 2] = cnt;
}

__global__ __launch_bounds__(256) void finalize_part(
    const float* __restrict__ ws, float* __restrict__ out) {
    const int i = blockIdx.x * blockDim.x + threadIdx.x;
    if (i >= N_SEG * N_P) return;
    const int s = i / N_P;
    const int p = i % N_P;

    float s1 = 0.f, s2 = 0.f, c = 0.f;
    for (int kc = 0; kc < N_CHUNK; ++kc) {
        const size_t base = ((size_t)(s * N_CHUNK + kc) * N_P + p) * 3;
        s1 += ws[base];
        s2 += ws[base + 1];
        c  += ws[base + 2];
    }

    float mean = s1 / c;                            // c==0 -> nan
    float var  = fmaxf(s2 / c - mean * mean, 0.f);
    float sd   = sqrtf(var);
    if (!(mean == mean)) mean = 0.f;
    if (!(sd == sd))     sd   = 0.f;

    out[s * 328 + p]       = mean;
    out[s * 328 + 164 + p] = sd;
}

// ---------------- atomic fallback (if ws too small) ----------------
__global__ __launch_bounds__(192) void accum_atomic(
    const float* __restrict__ frames, float* __restrict__ ws, int T) {
    const int s   = blockIdx.x;
    const int kc  = blockIdx.y;
    const int tid = threadIdx.x;
    if (tid >= N_P) return;

    const int off = landmark_offset(tid);
    int lo, hi;
    seg_bounds(s, T, &lo, &hi);

    float sum = 0.f, sq = 0.f, cnt = 0.f;
    int f = lo + kc;
    for (; f + 3 * N_CHUNK_AT < hi; f += 4 * N_CHUNK_AT) {
        float v0 = frames[(size_t)f * ROW + off];
        float v1 = frames[(size_t)(f + N_CHUNK_AT) * ROW + off];
        float v2 = frames[(size_t)(f + 2 * N_CHUNK_AT) * ROW + off];
        float v3 = frames[(size_t)(f + 3 * N_CHUNK_AT) * ROW + off];
        if (v0 == v0) { sum += v0; sq = fmaf(v0, v0, sq); cnt += 1.f; }
        if (v1 == v1) { sum += v1; sq = fmaf(v1, v1, sq); cnt += 1.f; }
        if (v2 == v2) { sum += v2; sq = fmaf(v2, v2, sq); cnt += 1.f; }
        if (v3 == v3) { sum += v3; sq = fmaf(v3, v3, sq); cnt += 1.f; }
    }
    for (; f < hi; f += N_CHUNK_AT) {
        float v = frames[(size_t)f * ROW + off];
        if (v == v) { sum += v; sq = fmaf(v, v, sq); cnt += 1.f; }
    }

    const int idx = s * N_P + tid;
    atomicAdd(&ws[idx],                 sum);
    atomicAdd(&ws[N_SEG * N_P + idx],   sq);
    atomicAdd(&ws[2 * N_SEG * N_P + idx], cnt);
}

__global__ __launch_bounds__(256) void finalize_atomic(
    const float* __restrict__ ws, float* __restrict__ out) {
    const int i = blockIdx.x * blockDim.x + threadIdx.x;
    if (i >= N_SEG * N_P) return;
    const int s = i / N_P;
    const int p = i % N_P;

    const float s1  = ws[i];
    const float s2  = ws[N_SEG * N_P + i];
    const float c   = ws[2 * N_SEG * N_P + i];

    float mean = s1 / c;
    float var  = fmaxf(s2 / c - mean * mean, 0.f);
    float sd   = sqrtf(var);
    if (!(mean == mean)) mean = 0.f;
    if (!(sd == sd))     sd   = 0.f;

    out[s * 328 + p]       = mean;
    out[s * 328 + 164 + p] = sd;
}

extern "C" void kernel_launch(void* const* d_in, const int* in_sizes, int n_in,
                              void* d_out, int out_size, void* d_ws, size_t ws_size,
                              hipStream_t stream) {
    const float* frames = (const float*)d_in[0];
    float* out = (float*)d_out;
    float* ws  = (float*)d_ws;
    const int T = in_sizes[0] / ROW;   // 32768

    const size_t need = (size_t)N_SEG * N_CHUNK * N_P * 3 * sizeof(float); // ~4.03 MB

    if (ws_size >= need) {
        dim3 grid(N_SEG, N_CHUNK);
        accum_part<<<grid, 192, 0, stream>>>(frames, ws, T);
        finalize_part<<<(N_SEG * N_P + 255) / 256, 256, 0, stream>>>(ws, out);
    } else {
        hipMemsetAsync(ws, 0, 3 * N_SEG * N_P * sizeof(float), stream);
        dim3 grid(N_SEG, N_CHUNK_AT);
        accum_atomic<<<grid, 192, 0, stream>>>(frames, ws, T);
        finalize_atomic<<<(N_SEG * N_P + 255) / 256, 256, 0, stream>>>(ws, out);
    }
}